// Round 1
// baseline (103.818 us; speedup 1.0000x reference)
//
#include <hip/hip_runtime.h>

#define N_NODES 10000
#define FEATS 32
#define HEADS 4
#define SAMPLES 256
#define N_BATCH 2048

// One block per edge n. Wave w (64 lanes) handles head w: 512 samples
// (256 from mid0/src-side, 256 from mid1/dst-side), 8 samples per lane.
// Softmax over the 512 samples + 8 sentinels (sentinel: logit=0, dist=1
// -> exp(1-1)=1 each, so +8 in the denominator, +0 in the numerator).
__global__ __launch_bounds__(256) void madgraph_kernel(
    const int* __restrict__ edge,        // (N_BATCH, 2)
    const int* __restrict__ mid0,        // (H, N_BATCH, S)
    const int* __restrict__ mid1,        // (H, N_BATCH, S)
    const float* __restrict__ pos,       // (H, N_NODES, F)
    const float* __restrict__ field,     // (H, N_NODES, F)
    const float* __restrict__ unc,       // scalar
    const float* __restrict__ edge_mat,  // (N_NODES, N_NODES), symmetric
    float* __restrict__ out)             // (N_BATCH)
{
    const int n    = blockIdx.x;
    const int tid  = threadIdx.x;
    const int wave = tid >> 6;   // head index
    const int lane = tid & 63;

    __shared__ float s_anchor[HEADS][2][FEATS]; // [h][0]=pos[h,src], [h][1]=pos[h,dst]
    __shared__ float s_field [HEADS][2][FEATS]; // [h][0]=field[h,dst], [h][1]=field[h,src]
    __shared__ float s_res[HEADS];

    const int src = edge[2 * n];
    const int dst = edge[2 * n + 1];
    const float U = unc[0];

    // Stage the 4 heads' anchor pos rows and field rows into LDS.
    for (int idx = tid; idx < HEADS * 2 * FEATS; idx += 256) {
        int h    = idx / (2 * FEATS);
        int r    = idx % (2 * FEATS);
        int side = r / FEATS;
        int f    = r % FEATS;
        int node_p = side ? dst : src;                 // anchor for diff
        int node_f = side ? src : dst;                 // field row for dot
        s_anchor[h][side][f] = pos  [(size_t)(h * N_NODES + node_p) * FEATS + f];
        s_field [h][side][f] = field[(size_t)(h * N_NODES + node_f) * FEATS + f];
    }
    __syncthreads();

    const int h = wave;
    float num = 0.f, den = 0.f;

    #pragma unroll
    for (int k = 0; k < 8; ++k) {
        int j    = lane + k * 64;     // 0..511
        int side = j >> 8;            // wave-uniform per k (k<4 -> 0, k>=4 -> 1)
        int s    = j & 255;
        const int* mid = side ? mid1 : mid0;
        int m = mid[((size_t)h * N_BATCH + n) * SAMPLES + s];

        const float4* pm = (const float4*)&pos[(size_t)(h * N_NODES + m) * FEATS];
        const float4* pa = (const float4*)&s_anchor[h][side][0];
        const float4* pf = (const float4*)&s_field [h][side][0];

        float dot = 0.f, nrm = 0.f;
        #pragma unroll
        for (int q = 0; q < 8; ++q) {
            float4 a = pa[q], b = pm[q], fv = pf[q];
            float dx = a.x - b.x, dy = a.y - b.y, dz = a.z - b.z, dw = a.w - b.w;
            dot += dx * fv.x + dy * fv.y + dz * fv.z + dw * fv.w;
            nrm += dx * dx + dy * dy + dz * dz + dw * dw;
        }

        // side0: edge_mat[m, dst] == edge_mat[dst, m] (symmetric matrix)
        // side1: edge_mat[src, m]
        int row = side ? src : dst;
        float em = edge_mat[(size_t)row * N_NODES + m];

        float logit = dot + U * em;
        float dist  = sqrtf(nrm);
        float e     = __expf(1.0f - dist);
        num += logit * e;
        den += e;
    }

    // Wave-wide butterfly reduction (64 lanes).
    #pragma unroll
    for (int off = 32; off > 0; off >>= 1) {
        num += __shfl_xor(num, off);
        den += __shfl_xor(den, off);
    }
    if (lane == 0) s_res[h] = num / (den + 8.0f);
    __syncthreads();

    if (tid == 0) {
        out[n] = 0.25f * (s_res[0] + s_res[1] + s_res[2] + s_res[3]);
    }
}

extern "C" void kernel_launch(void* const* d_in, const int* in_sizes, int n_in,
                              void* d_out, int out_size, void* d_ws, size_t ws_size,
                              hipStream_t stream) {
    const int*   edge     = (const int*)  d_in[0];
    const int*   mid0     = (const int*)  d_in[1];
    const int*   mid1     = (const int*)  d_in[2];
    const float* pos      = (const float*)d_in[3];
    const float* field    = (const float*)d_in[4];
    const float* unc      = (const float*)d_in[5];
    const float* edge_mat = (const float*)d_in[6];
    float*       out      = (float*)d_out;

    madgraph_kernel<<<N_BATCH, 256, 0, stream>>>(edge, mid0, mid1, pos, field,
                                                 unc, edge_mat, out);
}

// Round 2
// 88.169 us; speedup vs baseline: 1.1775x; 1.1775x over previous
//
#include <hip/hip_runtime.h>

#define N_NODES 10000
#define FEATS 32
#define HEADS 4
#define SAMPLES 256
#define N_BATCH 2048
#define CHUNK 64                      // samples staged per wave per iteration
#define NCHUNK ((2 * SAMPLES) / CHUNK) // 8

// Direct global->LDS DMA, 16 B per lane. Dest is wave-uniform base + lane*16.
__device__ __forceinline__ void gload_lds16(const float* g, float* l) {
    __builtin_amdgcn_global_load_lds(
        (const __attribute__((address_space(1))) void*)g,
        (__attribute__((address_space(3))) void*)l,
        16, 0, 0);
}

// One block per edge n; wave h handles head h (512 samples, 8 chunks of 64).
// Per chunk: wave DMAs 64 pos-rows (128 B each) into its private LDS region
// with coalesced 16B/lane loads (8 lanes per row), then each lane computes
// one sample entirely from LDS.
// Swizzle (rule: both-sides-or-neither with global_load_lds):
//   DMA dest is linear (lane l -> row l/8, slot l%8);
//   SOURCE chunk is pre-swizzled: lane l loads logical chunk (l&7)^(l>>3);
//   READ fetches logical chunk q from physical slot q^(row&7).
// => ds_read_b128 at the conflict-free 8-phase minimum.
__global__ __launch_bounds__(256) void madgraph_kernel(
    const int* __restrict__ edge,        // (N_BATCH, 2)
    const int* __restrict__ mid0,        // (H, N_BATCH, S)
    const int* __restrict__ mid1,        // (H, N_BATCH, S)
    const float* __restrict__ pos,       // (H, N_NODES, F)
    const float* __restrict__ field,     // (H, N_NODES, F)
    const float* __restrict__ unc,       // scalar
    const float* __restrict__ edge_mat,  // (N_NODES, N_NODES), symmetric
    float* __restrict__ out)             // (N_BATCH)
{
    const int n    = blockIdx.x;
    const int tid  = threadIdx.x;
    const int wave = tid >> 6;   // head index
    const int lane = tid & 63;

    __shared__ float s_rows[HEADS][CHUNK][FEATS]; // 4 * 8 KB = 32 KB
    __shared__ float s_res[HEADS];

    const int src = edge[2 * n];
    const int dst = edge[2 * n + 1];
    const float U = unc[0];

    const int h = wave;
    const int qsrc = (lane & 7) ^ (lane >> 3); // pre-swizzled source chunk

    float4 A[8], F[8];           // anchor pos row, field row (per side)
    float num = 0.f, den = 0.f;

    for (int c = 0; c < NCHUNK; ++c) {
        const int side = c >> 2;                 // chunks 0-3: side0, 4-7: side1
        if (c == 0 || c == 4) {
            // broadcast loads of the two 128 B rows for this side
            const float* pa = pos   + ((size_t)h * N_NODES + (side ? dst : src)) * FEATS;
            const float* pf = field + ((size_t)h * N_NODES + (side ? src : dst)) * FEATS;
            #pragma unroll
            for (int q = 0; q < 8; ++q) {
                A[q] = ((const float4*)pa)[q];
                F[q] = ((const float4*)pf)[q];
            }
        }
        const int* mids = side ? mid1 : mid0;
        const size_t sbase = ((size_t)h * N_BATCH + n) * SAMPLES + (c & 3) * CHUNK;
        const int m_own = mids[sbase + lane];    // sample node owned by this lane

        // Stage 64 rows: instr i covers rows [i*8, i*8+8), 8 lanes per row.
        #pragma unroll
        for (int i = 0; i < 8; ++i) {
            int row  = i * 8 + (lane >> 3);
            int mrow = __shfl(m_own, row);
            const float* gsrc = pos + ((size_t)h * N_NODES + mrow) * FEATS + qsrc * 4;
            gload_lds16(gsrc, &s_rows[h][i * 8][0]);
        }

        // edge-term gather (overlaps with the DMA latency):
        // side0: edge_mat[m, dst] == edge_mat[dst, m]; side1: edge_mat[src, m]
        const int rowsel = side ? src : dst;
        const float em = edge_mat[(size_t)rowsel * N_NODES + m_own];

        asm volatile("s_waitcnt vmcnt(0)" ::: "memory");
        __builtin_amdgcn_sched_barrier(0);

        // Each lane computes its own sample (row = lane) from LDS.
        float dot = 0.f, nrm = 0.f;
        #pragma unroll
        for (int q = 0; q < 8; ++q) {
            int s = q ^ (lane & 7);
            float4 b = *(const float4*)&s_rows[h][lane][s * 4];
            float4 a = A[q], fv = F[q];
            float dx = a.x - b.x, dy = a.y - b.y, dz = a.z - b.z, dw = a.w - b.w;
            dot += dx * fv.x + dy * fv.y + dz * fv.z + dw * fv.w;
            nrm += dx * dx + dy * dy + dz * dz + dw * dw;
        }

        float logit = dot + U * em;
        float dist  = sqrtf(nrm);
        float e     = __expf(1.0f - dist);
        num += logit * e;
        den += e;
    }

    // Wave-wide butterfly reduction (64 lanes).
    #pragma unroll
    for (int off = 32; off > 0; off >>= 1) {
        num += __shfl_xor(num, off);
        den += __shfl_xor(den, off);
    }
    if (lane == 0) s_res[h] = num / (den + 8.0f); // +8 sentinels: exp(1-1)=1 each
    __syncthreads();

    if (tid == 0) {
        out[n] = 0.25f * (s_res[0] + s_res[1] + s_res[2] + s_res[3]);
    }
}

extern "C" void kernel_launch(void* const* d_in, const int* in_sizes, int n_in,
                              void* d_out, int out_size, void* d_ws, size_t ws_size,
                              hipStream_t stream) {
    const int*   edge     = (const int*)  d_in[0];
    const int*   mid0     = (const int*)  d_in[1];
    const int*   mid1     = (const int*)  d_in[2];
    const float* pos      = (const float*)d_in[3];
    const float* field    = (const float*)d_in[4];
    const float* unc      = (const float*)d_in[5];
    const float* edge_mat = (const float*)d_in[6];
    float*       out      = (float*)d_out;

    madgraph_kernel<<<N_BATCH, 256, 0, stream>>>(edge, mid0, mid1, pos, field,
                                                 unc, edge_mat, out);
}

// Round 3
// 77.266 us; speedup vs baseline: 1.3436x; 1.1411x over previous
//
#include <hip/hip_runtime.h>

#define N_NODES 10000
#define FEATS 32
#define HEADS 4
#define SAMPLES 256
#define N_BATCH 2048
#define CHUNK 64                        // samples staged per wave per iteration
#define NCHUNK ((2 * SAMPLES) / CHUNK)  // 8
#define NGROUP 40                       // ceil(N_NODES / 256) groups per row
#define NWORDS (NGROUP * 4)             // 160 u64 bitmask words per row

// Direct global->LDS DMA, 16 B per lane. Dest is wave-uniform base + lane*16.
__device__ __forceinline__ void gload_lds16(const float* g, float* l) {
    __builtin_amdgcn_global_load_lds(
        (const __attribute__((address_space(1))) void*)g,
        (__attribute__((address_space(3))) void*)l,
        16, 0, 0);
}

// One block per edge n; wave h handles head h (512 samples, 8 chunks of 64).
//
// edge_mat values are exactly {-1,+1}; each block needs only rows `dst`
// (side0, via symmetry edge_mat[m,dst]==edge_mat[dst,m]) and `src` (side1).
// Block start: read both rows CONTIGUOUSLY (80 KB sequential HBM) and ballot
// sign bits into 2 x 1.25 KB LDS bitmasks. Per-sample edge term = LDS bit
// test -> +U/-U. This removes all random 128B HBM gathers from the loop.
//
// pos-row staging per chunk: wave DMAs 64 rows (128 B each) into LDS with
// coalesced 16B/lane global_load_lds (8 lanes per row). Swizzle is
// both-sides: linear DMA dest; SOURCE chunk pre-swizzled (l&7)^(l>>3);
// READ fetches logical chunk q from physical slot q^(lane&7).
__global__ __launch_bounds__(256) void madgraph_kernel(
    const int* __restrict__ edge,        // (N_BATCH, 2)
    const int* __restrict__ mid0,        // (H, N_BATCH, S)
    const int* __restrict__ mid1,        // (H, N_BATCH, S)
    const float* __restrict__ pos,       // (H, N_NODES, F)
    const float* __restrict__ field,     // (H, N_NODES, F)
    const float* __restrict__ unc,       // scalar
    const float* __restrict__ edge_mat,  // (N_NODES, N_NODES), +-1, symmetric
    float* __restrict__ out)             // (N_BATCH)
{
    const int n    = blockIdx.x;
    const int tid  = threadIdx.x;
    const int wave = tid >> 6;   // head index
    const int lane = tid & 63;

    __shared__ float s_rows[HEADS][CHUNK][FEATS];        // 32 KB
    __shared__ unsigned long long s_mask[2][NWORDS];     // 2.5 KB sign bitmasks
    __shared__ float s_res[HEADS];

    const int src = edge[2 * n];
    const int dst = edge[2 * n + 1];
    const float U = unc[0];

    // ---- edge_mat rows -> sign bitmasks (contiguous reads) ----
    // r=0: row dst (used by side0), r=1: row src (used by side1).
    #pragma unroll
    for (int r = 0; r < 2; ++r) {
        const float* rp = edge_mat + (size_t)(r ? src : dst) * N_NODES;
        for (int g = wave; g < NGROUP; g += HEADS) {
            int base = g * 256 + lane * 4;               // N_NODES % 4 == 0
            float4 v = make_float4(-1.f, -1.f, -1.f, -1.f);
            if (base < N_NODES) v = *(const float4*)(rp + base);
            unsigned long long b0 = __ballot(v.x > 0.f);
            unsigned long long b1 = __ballot(v.y > 0.f);
            unsigned long long b2 = __ballot(v.z > 0.f);
            unsigned long long b3 = __ballot(v.w > 0.f);
            if (lane == 0) {
                s_mask[r][g * 4 + 0] = b0;
                s_mask[r][g * 4 + 1] = b1;
                s_mask[r][g * 4 + 2] = b2;
                s_mask[r][g * 4 + 3] = b3;
            }
        }
    }
    __syncthreads();

    const int h = wave;
    const int qsrc = (lane & 7) ^ (lane >> 3); // pre-swizzled source chunk

    float4 A[8], F[8];           // anchor pos row, field row (per side)
    float num = 0.f, den = 0.f;

    for (int c = 0; c < NCHUNK; ++c) {
        const int side = c >> 2;                 // chunks 0-3: side0, 4-7: side1
        if (c == 0 || c == 4) {
            const float* pa = pos   + ((size_t)h * N_NODES + (side ? dst : src)) * FEATS;
            const float* pf = field + ((size_t)h * N_NODES + (side ? src : dst)) * FEATS;
            #pragma unroll
            for (int q = 0; q < 8; ++q) {
                A[q] = ((const float4*)pa)[q];
                F[q] = ((const float4*)pf)[q];
            }
        }
        const int* mids = side ? mid1 : mid0;
        const size_t sbase = ((size_t)h * N_BATCH + n) * SAMPLES + (c & 3) * CHUNK;
        const int m_own = mids[sbase + lane];    // sample node owned by this lane

        // Stage 64 rows: instr i covers rows [i*8, i*8+8), 8 lanes per row.
        #pragma unroll
        for (int i = 0; i < 8; ++i) {
            int row  = i * 8 + (lane >> 3);
            int mrow = __shfl(m_own, row);
            const float* gsrc = pos + ((size_t)h * N_NODES + mrow) * FEATS + qsrc * 4;
            gload_lds16(gsrc, &s_rows[h][i * 8][0]);
        }

        // edge term from LDS bitmask (no global load):
        // bit for node m lives in word (m>>8)*4 + (m&3), bit (m>>2)&63.
        const unsigned long long wbits = s_mask[side][((m_own >> 8) << 2) + (m_own & 3)];
        const float em = ((wbits >> ((m_own >> 2) & 63)) & 1ull) ? U : -U;

        asm volatile("s_waitcnt vmcnt(0)" ::: "memory");
        __builtin_amdgcn_sched_barrier(0);

        // Each lane computes its own sample (row = lane) from LDS.
        float dot = 0.f, nrm = 0.f;
        #pragma unroll
        for (int q = 0; q < 8; ++q) {
            int s = q ^ (lane & 7);
            float4 b = *(const float4*)&s_rows[h][lane][s * 4];
            float4 a = A[q], fv = F[q];
            float dx = a.x - b.x, dy = a.y - b.y, dz = a.z - b.z, dw = a.w - b.w;
            dot += dx * fv.x + dy * fv.y + dz * fv.z + dw * fv.w;
            nrm += dx * dx + dy * dy + dz * dz + dw * dw;
        }

        float logit = dot + em;
        float dist  = sqrtf(nrm);
        float e     = __expf(1.0f - dist);
        num += logit * e;
        den += e;
    }

    // Wave-wide butterfly reduction (64 lanes).
    #pragma unroll
    for (int off = 32; off > 0; off >>= 1) {
        num += __shfl_xor(num, off);
        den += __shfl_xor(den, off);
    }
    if (lane == 0) s_res[h] = num / (den + 8.0f); // +8 sentinels: exp(1-1)=1 each
    __syncthreads();

    if (tid == 0) {
        out[n] = 0.25f * (s_res[0] + s_res[1] + s_res[2] + s_res[3]);
    }
}

extern "C" void kernel_launch(void* const* d_in, const int* in_sizes, int n_in,
                              void* d_out, int out_size, void* d_ws, size_t ws_size,
                              hipStream_t stream) {
    const int*   edge     = (const int*)  d_in[0];
    const int*   mid0     = (const int*)  d_in[1];
    const int*   mid1     = (const int*)  d_in[2];
    const float* pos      = (const float*)d_in[3];
    const float* field    = (const float*)d_in[4];
    const float* unc      = (const float*)d_in[5];
    const float* edge_mat = (const float*)d_in[6];
    float*       out      = (float*)d_out;

    madgraph_kernel<<<N_BATCH, 256, 0, stream>>>(edge, mid0, mid1, pos, field,
                                                 unc, edge_mat, out);
}

// Round 4
// 69.478 us; speedup vs baseline: 1.4943x; 1.1121x over previous
//
#include <hip/hip_runtime.h>

#define N_NODES 10000
#define FEATS 32
#define HEADS 4
#define SAMPLES 256
#define N_BATCH 2048
#define CHUNK 64                        // samples staged per wave per iteration
#define NCHUNK ((2 * SAMPLES) / CHUNK)  // 8
#define NGROUP 40                       // ceil(N_NODES / 256) groups per row
#define NWORDS (NGROUP * 4)             // 160 u64 bitmask words per row

// Direct global->LDS DMA, 16 B per lane. Dest is wave-uniform base + lane*16.
__device__ __forceinline__ void gload_lds16(const float* g, float* l) {
    __builtin_amdgcn_global_load_lds(
        (const __attribute__((address_space(1))) void*)g,
        (__attribute__((address_space(3))) void*)l,
        16, 0, 0);
}

// ---------------- Kernel 1: edge_mat rows -> sign bitmasks in d_ws ----------
// Block n handles edge n: row dst (r=0, used by side0 via symmetry) and
// row src (r=1, side1). Pure streaming: 80 KB sequential HBM per block,
// 1.25 KB bitmask out per row. Also zeroes out[n] (k2 accumulates into it).
// ws layout: mask[n][r][w] u64, w in [0,160).
__global__ __launch_bounds__(256) void mask_kernel(
    const int* __restrict__ edge,
    const float* __restrict__ edge_mat,
    unsigned long long* __restrict__ ws_mask,
    float* __restrict__ out)
{
    const int n    = blockIdx.x;
    const int tid  = threadIdx.x;
    const int wave = tid >> 6;
    const int lane = tid & 63;

    const int src = edge[2 * n];
    const int dst = edge[2 * n + 1];
    if (tid == 0) out[n] = 0.f;

    unsigned long long* wsn = ws_mask + (size_t)n * 2 * NWORDS;

    #pragma unroll
    for (int r = 0; r < 2; ++r) {
        const float* rp = edge_mat + (size_t)(r ? src : dst) * N_NODES;
        for (int g = wave; g < NGROUP; g += 4) {
            int base = g * 256 + lane * 4;
            float4 v = make_float4(-1.f, -1.f, -1.f, -1.f);
            if (base < N_NODES) v = *(const float4*)(rp + base);
            unsigned long long b0 = __ballot(v.x > 0.f);
            unsigned long long b1 = __ballot(v.y > 0.f);
            unsigned long long b2 = __ballot(v.z > 0.f);
            unsigned long long b3 = __ballot(v.w > 0.f);
            if (lane < 4) {
                unsigned long long b = lane == 0 ? b0 : lane == 1 ? b1
                                     : lane == 2 ? b2 : b3;
                wsn[r * NWORDS + g * 4 + lane] = b;
            }
        }
    }
}

// ---------------- Kernel 2: main compute, one wave per (edge, head) ---------
// blockIdx.x = i in [0, 8192): h = i & 3, n = i >> 2. With round-robin
// XCD assignment (XCD = i % 8), XCD x only touches pos[x & 3] (1.28 MB)
// -> pos-row gathers are per-XCD L2-resident instead of thrashing L3.
// pos-row staging swizzle is both-sides: linear DMA dest; SOURCE chunk
// pre-swizzled (l&7)^(l>>3); READ logical chunk q from slot q^(lane&7).
__global__ __launch_bounds__(64) void madgraph_kernel(
    const int* __restrict__ edge,
    const int* __restrict__ mid0,
    const int* __restrict__ mid1,
    const float* __restrict__ pos,
    const float* __restrict__ field,
    const float* __restrict__ unc,
    const unsigned long long* __restrict__ ws_mask,
    float* __restrict__ out)
{
    const int i    = blockIdx.x;
    const int h    = i & 3;
    const int n    = i >> 2;
    const int lane = threadIdx.x;

    __shared__ float s_rows[CHUNK][FEATS];            // 8 KB
    __shared__ unsigned long long s_mask[2 * NWORDS]; // 2.5 KB

    const int src = edge[2 * n];
    const int dst = edge[2 * n + 1];
    const float U = unc[0];

    // Stage this edge's two bitmask rows (coalesced 2.5 KB from ws).
    const unsigned long long* wsn = ws_mask + (size_t)n * 2 * NWORDS;
    #pragma unroll
    for (int w = 0; w < 2 * NWORDS / 64; ++w)
        s_mask[w * 64 + lane] = wsn[w * 64 + lane];
    __syncthreads();

    const int qsrc = (lane & 7) ^ (lane >> 3); // pre-swizzled source chunk

    float4 A[8], F[8];
    float num = 0.f, den = 0.f;

    for (int c = 0; c < NCHUNK; ++c) {
        const int side = c >> 2;
        if (c == 0 || c == 4) {
            const float* pa = pos   + ((size_t)h * N_NODES + (side ? dst : src)) * FEATS;
            const float* pf = field + ((size_t)h * N_NODES + (side ? src : dst)) * FEATS;
            #pragma unroll
            for (int q = 0; q < 8; ++q) {
                A[q] = ((const float4*)pa)[q];
                F[q] = ((const float4*)pf)[q];
            }
        }
        const int* mids = side ? mid1 : mid0;
        const size_t sbase = ((size_t)h * N_BATCH + n) * SAMPLES + (c & 3) * CHUNK;
        const int m_own = mids[sbase + lane];

        // Stage 64 rows: instr i covers rows [i*8, i*8+8), 8 lanes per row.
        #pragma unroll
        for (int t = 0; t < 8; ++t) {
            int row  = t * 8 + (lane >> 3);
            int mrow = __shfl(m_own, row);
            const float* gsrc = pos + ((size_t)h * N_NODES + mrow) * FEATS + qsrc * 4;
            gload_lds16(gsrc, &s_rows[t * 8][0]);
        }

        // edge term from LDS bitmask (no global load)
        const unsigned long long wbits =
            s_mask[side * NWORDS + ((m_own >> 8) << 2) + (m_own & 3)];
        const float em = ((wbits >> ((m_own >> 2) & 63)) & 1ull) ? U : -U;

        asm volatile("s_waitcnt vmcnt(0)" ::: "memory");
        __builtin_amdgcn_sched_barrier(0);

        float dot = 0.f, nrm = 0.f;
        #pragma unroll
        for (int q = 0; q < 8; ++q) {
            int s = q ^ (lane & 7);
            float4 b = *(const float4*)&s_rows[lane][s * 4];
            float4 a = A[q], fv = F[q];
            float dx = a.x - b.x, dy = a.y - b.y, dz = a.z - b.z, dw = a.w - b.w;
            dot += dx * fv.x + dy * fv.y + dz * fv.z + dw * fv.w;
            nrm += dx * dx + dy * dy + dz * dz + dw * dw;
        }

        float logit = dot + em;
        float dist  = sqrtf(nrm);
        float e     = __expf(1.0f - dist);
        num += logit * e;
        den += e;
    }

    #pragma unroll
    for (int off = 32; off > 0; off >>= 1) {
        num += __shfl_xor(num, off);
        den += __shfl_xor(den, off);
    }
    if (lane == 0) {
        // +8 sentinels: exp(1-1)=1 each. Mean over heads via atomic accumulate
        // (k1 zeroed out[n] this call, so replays stay idempotent).
        atomicAdd(out + n, 0.25f * (num / (den + 8.0f)));
    }
}

extern "C" void kernel_launch(void* const* d_in, const int* in_sizes, int n_in,
                              void* d_out, int out_size, void* d_ws, size_t ws_size,
                              hipStream_t stream) {
    const int*   edge     = (const int*)  d_in[0];
    const int*   mid0     = (const int*)  d_in[1];
    const int*   mid1     = (const int*)  d_in[2];
    const float* pos      = (const float*)d_in[3];
    const float* field    = (const float*)d_in[4];
    const float* unc      = (const float*)d_in[5];
    const float* edge_mat = (const float*)d_in[6];
    float*       out      = (float*)d_out;
    unsigned long long* ws_mask = (unsigned long long*)d_ws; // 5.24 MB used

    mask_kernel<<<N_BATCH, 256, 0, stream>>>(edge, edge_mat, ws_mask, out);
    madgraph_kernel<<<N_BATCH * HEADS, 64, 0, stream>>>(edge, mid0, mid1, pos,
                                                        field, unc, ws_mask, out);
}